// Round 1
// baseline (434.756 us; speedup 1.0000x reference)
//
#include <hip/hip_runtime.h>

// TripletLoss: pairs are (2i, 2i+1); label[2i]==0 -> row 2i is positive.
// loss = mean_i relu(d(proto,pos_i) - d(proto,neg_i) + margin), fp32.

#define PAIRS_PER_WAVE 16
#define BLOCK_THREADS 256
#define WAVES_PER_BLOCK (BLOCK_THREADS / 64)

__global__ void tl_zero_out(float* out) {
    if (threadIdx.x == 0) out[0] = 0.0f;
}

__global__ __launch_bounds__(BLOCK_THREADS) void tl_main(
    const float* __restrict__ proto,
    const float* __restrict__ emb,
    const int* __restrict__ label,
    const int* __restrict__ margin_p,
    float* __restrict__ out,
    int n_pairs)
{
    const int lane = threadIdx.x & 63;
    const int wave = blockIdx.x * WAVES_PER_BLOCK + (threadIdx.x >> 6);

    // margin: robust to int32 or fp32 storage of the Python scalar 1
    int mbits = margin_p[0];
    float margin = (mbits >= -1000000 && mbits <= 1000000)
                       ? (float)mbits
                       : __int_as_float(mbits);

    // lane l holds proto[4l .. 4l+3]; 64 lanes * 4 = 256 = D
    const float4 p = ((const float4*)proto)[lane];

    float acc = 0.0f;
    const int base = wave * PAIRS_PER_WAVE;

    for (int k = 0; k < PAIRS_PER_WAVE; ++k) {
        const int pair = base + k;
        if (pair >= n_pairs) break;

        const float4* row = (const float4*)(emb + (size_t)(2 * pair) * 256);
        const float4 x0 = row[lane];        // row 2*pair
        const float4 x1 = row[64 + lane];   // row 2*pair + 1

        float dx, d0, d1;
        dx = p.x - x0.x; d0 = dx * dx;
        dx = p.y - x0.y; d0 = fmaf(dx, dx, d0);
        dx = p.z - x0.z; d0 = fmaf(dx, dx, d0);
        dx = p.w - x0.w; d0 = fmaf(dx, dx, d0);

        dx = p.x - x1.x; d1 = dx * dx;
        dx = p.y - x1.y; d1 = fmaf(dx, dx, d1);
        dx = p.z - x1.z; d1 = fmaf(dx, dx, d1);
        dx = p.w - x1.w; d1 = fmaf(dx, dx, d1);

        // label of the even row decides which is the positive
        const int l0 = label[2 * pair];
        float part = (l0 == 0) ? (d0 - d1) : (d1 - d0);

        // 64-lane butterfly reduce: every lane ends with the pair's delta
        #pragma unroll
        for (int off = 32; off > 0; off >>= 1)
            part += __shfl_xor(part, off, 64);

        const float loss = part + margin;
        acc += (loss > 0.0f) ? loss : 0.0f;
    }

    if (lane == 0)
        atomicAdd(out, acc / (float)n_pairs);
}

extern "C" void kernel_launch(void* const* d_in, const int* in_sizes, int n_in,
                              void* d_out, int out_size, void* d_ws, size_t ws_size,
                              hipStream_t stream) {
    const float* proto = (const float*)d_in[0];
    const float* emb   = (const float*)d_in[1];
    const int*   label = (const int*)d_in[2];
    const int*   marg  = (const int*)d_in[3];
    float* out = (float*)d_out;

    const int n = in_sizes[2];        // 262144
    const int n_pairs = n / 2;        // 131072

    tl_zero_out<<<1, 64, 0, stream>>>(out);

    const int waves = (n_pairs + PAIRS_PER_WAVE - 1) / PAIRS_PER_WAVE;       // 8192
    const int blocks = (waves + WAVES_PER_BLOCK - 1) / WAVES_PER_BLOCK;      // 2048
    tl_main<<<blocks, BLOCK_THREADS, 0, stream>>>(proto, emb, label, marg, out, n_pairs);
}

// Round 2
// 372.562 us; speedup vs baseline: 1.1669x; 1.1669x over previous
//
#include <hip/hip_runtime.h>

// TripletLoss: pairs are (2i, 2i+1); label[2i]==0 -> row 2i is positive.
// loss = mean_i relu(d(proto,pos_i) - d(proto,neg_i) + margin), fp32 scalar.
//
// R2 structure: one row per thread (262144 threads). Each thread streams its
// 1KB row with float4 loads; proto lives in LDS (broadcast reads). One
// shfl_xor(1) per pair, one butterfly per wave (amortized over 32 pairs),
// one atomicAdd per block.

#define BLOCK_THREADS 256

__global__ void tl_zero_out(float* out) {
    if (threadIdx.x == 0) out[0] = 0.0f;
}

__global__ __launch_bounds__(BLOCK_THREADS) void tl_main(
    const float* __restrict__ proto,
    const float* __restrict__ emb,
    const int* __restrict__ label,
    const int* __restrict__ margin_p,
    float* __restrict__ out,
    int n_pairs)
{
    __shared__ float4 sproto[64];     // 1KB: proto[256]
    __shared__ float swave[4];        // per-wave partials

    const int tid = threadIdx.x;
    const int row = blockIdx.x * BLOCK_THREADS + tid;

    // margin: robust to int32 or fp32 storage of the Python scalar 1
    int mbits = margin_p[0];
    float margin = (mbits >= -1000000 && mbits <= 1000000)
                       ? (float)mbits
                       : __int_as_float(mbits);

    // stage proto into LDS (all waves read it broadcast-style)
    if (tid < 64) sproto[tid] = ((const float4*)proto)[tid];

    // issue the label load early (coalesced; only even lanes consume it)
    const int l0 = label[row];

    __syncthreads();

    // stream this thread's row: 64 float4 loads, 4 independent accumulators
    const float4* __restrict__ r = (const float4*)(emb + (size_t)row * 256);

    float a0 = 0.0f, a1 = 0.0f, a2 = 0.0f, a3 = 0.0f;

    #pragma unroll 4
    for (int j = 0; j < 16; ++j) {
        const int b = j * 4;
        float4 x0 = r[b + 0];
        float4 x1 = r[b + 1];
        float4 x2 = r[b + 2];
        float4 x3 = r[b + 3];
        float4 p0 = sproto[b + 0];
        float4 p1 = sproto[b + 1];
        float4 p2 = sproto[b + 2];
        float4 p3 = sproto[b + 3];

        float dx;
        dx = p0.x - x0.x; a0 = fmaf(dx, dx, a0);
        dx = p0.y - x0.y; a1 = fmaf(dx, dx, a1);
        dx = p0.z - x0.z; a2 = fmaf(dx, dx, a2);
        dx = p0.w - x0.w; a3 = fmaf(dx, dx, a3);
        dx = p1.x - x1.x; a0 = fmaf(dx, dx, a0);
        dx = p1.y - x1.y; a1 = fmaf(dx, dx, a1);
        dx = p1.z - x1.z; a2 = fmaf(dx, dx, a2);
        dx = p1.w - x1.w; a3 = fmaf(dx, dx, a3);
        dx = p2.x - x2.x; a0 = fmaf(dx, dx, a0);
        dx = p2.y - x2.y; a1 = fmaf(dx, dx, a1);
        dx = p2.z - x2.z; a2 = fmaf(dx, dx, a2);
        dx = p2.w - x2.w; a3 = fmaf(dx, dx, a3);
        dx = p3.x - x3.x; a0 = fmaf(dx, dx, a0);
        dx = p3.y - x3.y; a1 = fmaf(dx, dx, a1);
        dx = p3.z - x3.z; a2 = fmaf(dx, dx, a2);
        dx = p3.w - x3.w; a3 = fmaf(dx, dx, a3);
    }

    const float d = (a0 + a1) + (a2 + a3);

    // exchange with pair partner (rows 2i / 2i+1 are adjacent lanes)
    const float other = __shfl_xor(d, 1, 64);

    float acc = 0.0f;
    if ((tid & 1) == 0) {
        // even lane holds row 2i; l0 = label[2i]. label==0 -> this row positive.
        const float delta = (l0 == 0) ? (d - other) : (other - d);
        const float loss = delta + margin;
        acc = (loss > 0.0f) ? loss : 0.0f;
    }

    // one butterfly per wave (amortized over 32 pairs)
    #pragma unroll
    for (int off = 32; off > 0; off >>= 1)
        acc += __shfl_xor(acc, off, 64);

    const int lane = tid & 63;
    const int wid = tid >> 6;
    if (lane == 0) swave[wid] = acc;
    __syncthreads();

    if (tid == 0) {
        float s = (swave[0] + swave[1]) + (swave[2] + swave[3]);
        atomicAdd(out, s / (float)n_pairs);
    }
}

extern "C" void kernel_launch(void* const* d_in, const int* in_sizes, int n_in,
                              void* d_out, int out_size, void* d_ws, size_t ws_size,
                              hipStream_t stream) {
    const float* proto = (const float*)d_in[0];
    const float* emb   = (const float*)d_in[1];
    const int*   label = (const int*)d_in[2];
    const int*   marg  = (const int*)d_in[3];
    float* out = (float*)d_out;

    const int n_rows = in_sizes[2];      // 262144
    const int n_pairs = n_rows / 2;      // 131072

    tl_zero_out<<<1, 64, 0, stream>>>(out);

    const int blocks = n_rows / BLOCK_THREADS;   // 1024
    tl_main<<<blocks, BLOCK_THREADS, 0, stream>>>(proto, emb, label, marg, out, n_pairs);
}

// Round 3
// 359.597 us; speedup vs baseline: 1.2090x; 1.0361x over previous
//
#include <hip/hip_runtime.h>

// TripletLoss: pairs are (2i, 2i+1); label[2i]==0 -> row 2i is positive.
// loss = mean_i relu(d(proto,pos_i) - d(proto,neg_i) + margin), fp32 scalar.
//
// R3 structure: wave-per-row coalesced loads (64 lanes x float4 = one 1KB row
// per instruction -> every cache line fully consumed immediately, no L1
// thrash), 4 pairs (8 rows / 8KB) in flight per iteration with explicit
// prefetch of the next 8 rows, signed per-lane delta so only ONE 6-step
// butterfly per pair, shuffles for the 4 pairs interleaved (independent
// chains). 16 pairs per wave, contiguous 32KB chunk -> clean L2 streaming.

#define BLOCK_THREADS 256
#define WAVES_PER_BLOCK 4
#define PAIRS_PER_ITER 4
#define ITERS 4                    // 16 pairs per wave

__global__ void tl_zero_out(float* out) {
    if (threadIdx.x == 0) out[0] = 0.0f;
}

__global__ __launch_bounds__(BLOCK_THREADS) void tl_main(
    const float* __restrict__ proto,
    const float* __restrict__ emb,
    const int* __restrict__ label,
    const int* __restrict__ margin_p,
    float* __restrict__ out,
    int n_pairs)
{
    __shared__ float swave[WAVES_PER_BLOCK];

    const int lane = threadIdx.x & 63;
    const int wv   = threadIdx.x >> 6;
    const int wave = blockIdx.x * WAVES_PER_BLOCK + wv;
    const int pair_base = wave * (PAIRS_PER_ITER * ITERS);

    // margin: robust to int32 or fp32 storage of the Python scalar 1
    int mbits = margin_p[0];
    float margin = (mbits >= -1000000 && mbits <= 1000000)
                       ? (float)mbits
                       : __int_as_float(mbits);

    // lane l holds proto[4l..4l+3]: one coalesced 1KB read, L2/L3-hot
    const float4 p = ((const float4*)proto)[lane];

    // hoist all 16 pair labels (wave-uniform addresses, overlap latency)
    int lb[ITERS][PAIRS_PER_ITER];
    #pragma unroll
    for (int it = 0; it < ITERS; ++it)
        #pragma unroll
        for (int q = 0; q < PAIRS_PER_ITER; ++q)
            lb[it][q] = label[2 * (pair_base + it * PAIRS_PER_ITER + q)];

    // this wave's 32 contiguous rows start here
    const float4* __restrict__ rows =
        (const float4*)(emb + (size_t)pair_base * 2 * 256);

    // prime: batch 0 (8 rows; float4-index of row r = r*64 + lane)
    float4 x[2 * PAIRS_PER_ITER];
    #pragma unroll
    for (int r = 0; r < 8; ++r) x[r] = rows[r * 64 + lane];

    float acc = 0.0f;

    #pragma unroll
    for (int it = 0; it < ITERS; ++it) {
        // prefetch next batch while we reduce the current one
        float4 y[8];
        if (it + 1 < ITERS) {
            const float4* nrows = rows + (it + 1) * 8 * 64;
            #pragma unroll
            for (int r = 0; r < 8; ++r) y[r] = nrows[r * 64 + lane];
        }

        // per-lane signed delta for each of 4 pairs
        float s[PAIRS_PER_ITER];
        #pragma unroll
        for (int q = 0; q < PAIRS_PER_ITER; ++q) {
            const float4 e0 = x[2 * q];       // row 2*pair   (even: label lb)
            const float4 e1 = x[2 * q + 1];   // row 2*pair+1
            float dx, d0, d1;
            dx = p.x - e0.x; d0 = dx * dx;
            dx = p.y - e0.y; d0 = fmaf(dx, dx, d0);
            dx = p.z - e0.z; d0 = fmaf(dx, dx, d0);
            dx = p.w - e0.w; d0 = fmaf(dx, dx, d0);
            dx = p.x - e1.x; d1 = dx * dx;
            dx = p.y - e1.y; d1 = fmaf(dx, dx, d1);
            dx = p.z - e1.z; d1 = fmaf(dx, dx, d1);
            dx = p.w - e1.w; d1 = fmaf(dx, dx, d1);
            s[q] = (lb[it][q] == 0) ? (d0 - d1) : (d1 - d0);
        }

        // 4 independent 6-step butterflies, interleaved to hide bpermute latency
        #pragma unroll
        for (int off = 32; off > 0; off >>= 1) {
            #pragma unroll
            for (int q = 0; q < PAIRS_PER_ITER; ++q)
                s[q] += __shfl_xor(s[q], off, 64);
        }

        #pragma unroll
        for (int q = 0; q < PAIRS_PER_ITER; ++q) {
            const float loss = s[q] + margin;
            acc += (loss > 0.0f) ? loss : 0.0f;
        }

        if (it + 1 < ITERS) {
            #pragma unroll
            for (int r = 0; r < 8; ++r) x[r] = y[r];
        }
    }

    // after a full butterfly every lane holds the wave total
    if (lane == 0) swave[wv] = acc;
    __syncthreads();

    if (threadIdx.x == 0) {
        const float s = (swave[0] + swave[1]) + (swave[2] + swave[3]);
        atomicAdd(out, s / (float)n_pairs);
    }
}

extern "C" void kernel_launch(void* const* d_in, const int* in_sizes, int n_in,
                              void* d_out, int out_size, void* d_ws, size_t ws_size,
                              hipStream_t stream) {
    const float* proto = (const float*)d_in[0];
    const float* emb   = (const float*)d_in[1];
    const int*   label = (const int*)d_in[2];
    const int*   marg  = (const int*)d_in[3];
    float* out = (float*)d_out;

    const int n_rows  = in_sizes[2];      // 262144
    const int n_pairs = n_rows / 2;       // 131072

    tl_zero_out<<<1, 64, 0, stream>>>(out);

    // each wave: 16 pairs = 32 rows; each block: 4 waves = 128 rows
    const int blocks = n_rows / (WAVES_PER_BLOCK * PAIRS_PER_ITER * ITERS * 2); // 2048
    tl_main<<<blocks, BLOCK_THREADS, 0, stream>>>(proto, emb, label, marg, out, n_pairs);
}